// Round 6
// baseline (449.107 us; speedup 1.0000x reference)
//
#include <hip/hip_runtime.h>
#include <math.h>

#define BN_EPS 1e-5f

typedef _Float16 half8 __attribute__((ext_vector_type(8)));
typedef float floatx16 __attribute__((ext_vector_type(16)));

// ---------------------------------------------------------------------------
// Kernel A: conv1 (k=3, pad=1, 1->16 ch) + ReLU, and channel means (pooled).
// ---------------------------------------------------------------------------
__global__ __launch_bounds__(256) void conv1_kernel(
    const float* __restrict__ x, const float* __restrict__ w,
    const float* __restrict__ bias, float* __restrict__ h,
    float* __restrict__ pooled) {
  __shared__ float xs[514];
  __shared__ float psum[256];
  const int b = blockIdx.x;
  const int t = threadIdx.x;
  for (int i = t; i < 512; i += 256) xs[i + 1] = x[b * 512 + i];
  if (t == 0) { xs[0] = 0.f; xs[513] = 0.f; }
  __syncthreads();
  const int c  = t >> 4;
  const int l0 = (t & 15) * 32;
  const float w0 = w[c * 3 + 0], w1 = w[c * 3 + 1], w2 = w[c * 3 + 2];
  const float bb = bias[c];
  float s = 0.f;
  float* hrow = h + ((size_t)b * 16 + c) * 512;
  for (int j = 0; j < 32; ++j) {
    const int l = l0 + j;
    float v = fmaf(w0, xs[l], fmaf(w1, xs[l + 1], fmaf(w2, xs[l + 2], bb)));
    v = fmaxf(v, 0.f);
    hrow[l] = v;
    s += v;
  }
  psum[t] = s;
  __syncthreads();
  if ((t & 15) == 0) {
    float tot = 0.f;
    for (int k = 0; k < 16; ++k) tot += psum[t + k];
    pooled[b * 16 + c] = tot * (1.f / 512.f);
  }
}

// ---------------------------------------------------------------------------
// Kernel B: router. softmax -> top2 -> renormalized gates + cv^2 scalar.
// ---------------------------------------------------------------------------
__global__ void router_kernel(const float* __restrict__ pooled,
                              const float* __restrict__ rw,
                              const float* __restrict__ rb,
                              float* __restrict__ pair_g,
                              int* __restrict__ pair_e,
                              float* __restrict__ out_cv) {
  __shared__ float probs_l[64][8];
  __shared__ float mp[8];
  const int t = threadIdx.x;
  {
    float pl[16];
    for (int c = 0; c < 16; ++c) pl[c] = pooled[t * 16 + c];
    float lg[8];
    float mx = -1e30f;
    for (int e = 0; e < 8; ++e) {
      float a = rb[e];
      for (int c = 0; c < 16; ++c) a = fmaf(pl[c], rw[e * 16 + c], a);
      lg[e] = a;
      mx = fmaxf(mx, a);
    }
    float sum = 0.f;
    for (int e = 0; e < 8; ++e) { lg[e] = expf(lg[e] - mx); sum += lg[e]; }
    const float inv = 1.f / sum;
    for (int e = 0; e < 8; ++e) { lg[e] *= inv; probs_l[t][e] = lg[e]; }
    int e1 = 0; float p1 = lg[0];
    for (int e = 1; e < 8; ++e) if (lg[e] > p1) { p1 = lg[e]; e1 = e; }
    int e2 = -1; float p2 = -1.f;
    for (int e = 0; e < 8; ++e) if (e != e1 && lg[e] > p2) { p2 = lg[e]; e2 = e; }
    const float gs = 1.f / (p1 + p2);
    pair_e[2 * t]     = e1; pair_g[2 * t]     = p1 * gs;
    pair_e[2 * t + 1] = e2; pair_g[2 * t + 1] = p2 * gs;
  }
  __syncthreads();
  if (t < 8) {
    float s = 0.f;
    for (int b = 0; b < 64; ++b) s += probs_l[b][t];
    mp[t] = s * (1.f / 64.f);
  }
  __syncthreads();
  if (t == 0) {
    float mean = 0.f;
    for (int e = 0; e < 8; ++e) mean += mp[e];
    mean *= (1.f / 8.f);
    float var = 0.f;
    for (int e = 0; e < 8; ++e) { const float d = mp[e] - mean; var = fmaf(d, d, var); }
    var *= (1.f / 7.f);
    const float cv = sqrtf(var) / (mean + 1e-10f);
    *out_cv = cv * cv;
  }
}

// ---------------------------------------------------------------------------
// Weight repack: ew[e][co][ci][k] fp32 -> wrp[e][cic][dkp][co][ci32] fp16,
// dk padded to KP with zero taps (RING | KP in the consumer).
// ---------------------------------------------------------------------------
template <int CI, int K, int KP, int CO>
__global__ __launch_bounds__(256) void repack_kernel(
    const float* __restrict__ ew, _Float16* __restrict__ wrp) {
  constexpr int NCc = CI / 32;
  const int tid = blockIdx.x * 256 + threadIdx.x;
  const int c32 = tid & 31;
  int r = tid >> 5;
  const int co = r % CO; r /= CO;
  const int cic = r % NCc;
  const int e = r / NCc;
  const float* src = ew + ((size_t)(e * CO + co) * CI + cic * 32 + c32) * K;
  float v[K];
#pragma unroll
  for (int dk = 0; dk < K; ++dk) v[dk] = src[dk];
#pragma unroll
  for (int dk = 0; dk < KP; ++dk)
    wrp[(((size_t)(e * NCc + cic) * KP + dk) * CO + co) * 32 + c32] =
        (_Float16)(dk < K ? v[dk] : 0.f);
}

// ---------------------------------------------------------------------------
// Block1 (fp32 vector conv, 16->64ch, L512->256), fp16 [pair][xp][co] out.
// ---------------------------------------------------------------------------
__global__ __launch_bounds__(256) void conv_block1(
    const float* __restrict__ in, const float* __restrict__ ew,
    const float* __restrict__ eb, const float* __restrict__ eg,
    const float* __restrict__ ebb, const float* __restrict__ em,
    const float* __restrict__ ev, const int* __restrict__ pair_e,
    _Float16* __restrict__ out) {
  constexpr int CI = 16, LIN = 512, K = 3, PAD = 1, CO = 64;
  constexpr int W_X  = 66;
  constexpr int W_XP = 68;
  constexpr int WROW = 66;
  __shared__ __align__(16) float xs[CI * W_XP];
  __shared__ __align__(16) float wls[CI * K * WROW];

  const int p  = blockIdx.y;
  const int t  = threadIdx.x;
  const int e  = pair_e[p];
  const int jt = blockIdx.x;
  const float* inp = in + (size_t)(p >> 1) * CI * LIN;
  const int cg = t & 31;
  const int jg = t >> 5;

  float acc0[8], acc1[8];
#pragma unroll
  for (int u = 0; u < 8; ++u) { acc0[u] = 0.f; acc1[u] = 0.f; }
  const int gx0 = jt * 64 - PAD;

  for (int i = t; i < CI * W_XP; i += 256) {
    const int ci = i / W_XP, w = i % W_XP;
    const int gi = gx0 + w;
    float v = 0.f;
    if (w < W_X && gi >= 0 && gi < LIN) v = inp[(size_t)ci * LIN + gi];
    xs[i] = v;
  }
  for (int i = t; i < CI * K * 64; i += 256) {
    const int co = i / (CI * K);
    const int r  = i % (CI * K);
    const int ci = r / K, k = r % K;
    wls[(ci * K + k) * WROW + co] =
        ew[(((size_t)e * CO + co) * CI + ci) * K + k];
  }
  __syncthreads();
  for (int ci = 0; ci < CI; ++ci) {
    const float* xrow = xs + ci * W_XP + jg * 8;
    const float* wrow = wls + ci * K * WROW + 2 * cg;
    float xw[8];
    {
      const float4 a = *(const float4*)(xrow);
      const float4 b = *(const float4*)(xrow + 4);
      xw[0] = a.x; xw[1] = a.y; xw[2] = a.z; xw[3] = a.w;
      xw[4] = b.x; xw[5] = b.y; xw[6] = b.z; xw[7] = b.w;
    }
#pragma unroll
    for (int dk = 0; dk < K; ++dk) {
      const float2 wv = *(const float2*)(wrow + dk * WROW);
#pragma unroll
      for (int u = 0; u < 8; ++u) {
        const float xv = xw[(dk + u) & 7];
        acc0[u] = fmaf(wv.x, xv, acc0[u]);
        acc1[u] = fmaf(wv.y, xv, acc1[u]);
      }
      if (dk + 1 < K) xw[dk & 7] = xrow[dk + 8];
    }
  }

  const int j0 = jt * 32 + jg * 4;
#pragma unroll
  for (int n = 0; n < 2; ++n) {
    const float* acc = n ? acc1 : acc0;
    const int co = 2 * cg + n;
    const int pe = e * CO + co;
    const float s   = eg[pe] * rsqrtf(ev[pe] + BN_EPS);
    const float off = fmaf(eb[pe] - em[pe], s, ebb[pe]);
#pragma unroll
    for (int q = 0; q < 4; ++q) {
      const float y0 = fmaxf(fmaf(acc[2 * q], s, off), 0.f);
      const float y1 = fmaxf(fmaf(acc[2 * q + 1], s, off), 0.f);
      out[((size_t)p * 256 + j0 + q) * CO + co] = (_Float16)fmaxf(y0, y1);
    }
  }
}

// ---------------------------------------------------------------------------
// MFMA conv block v3 (see R6 notes): A global->VGPR ring, B LDS dbuf with
// rotate swizzle, register-double-buffered B fragments, full KP unroll.
// ---------------------------------------------------------------------------
template <int CI, int K, int KP, int PAD, int CO, int WM, int WN, int MT,
          int NT, int LIN, int RING>
__global__ __launch_bounds__(256, 1) void mfma_conv(
    const _Float16* __restrict__ xin, const _Float16* __restrict__ wrp,
    const float* __restrict__ eb, const float* __restrict__ eg,
    const float* __restrict__ ebb, const float* __restrict__ em,
    const float* __restrict__ ev, const int* __restrict__ pair_e,
    _Float16* __restrict__ out) {
  constexpr int BM  = WM * MT * 32;
  constexpr int XN  = WN * NT * 32;
  constexpr int NC  = CI / 32;
  constexpr int NPH = NC * KP;
  constexpr int XWR = XN + KP - 1;
  constexpr int XTN = LIN / XN;
  static_assert(KP % RING == 0, "RING must divide KP");

  __shared__ __align__(16) _Float16 Bsh[2][XWR * 32];
  __shared__ float sc[BM];
  __shared__ float of[BM];

  const int p  = blockIdx.y;
  const int t  = threadIdx.x;
  const int e  = pair_e[p];
  const int xt = blockIdx.x % XTN;
  const int ct = blockIdx.x / XTN;
  const int cob = ct * BM;
  const int x0  = xt * XN;

  const int lane = t & 63;
  const int wave = t >> 6;
  const int wm = wave / WN;
  const int wn = wave % WN;
  const int l31 = lane & 31;
  const int lhi = lane >> 5;

  for (int i = t; i < BM; i += 256) {
    const int pe = e * CO + cob + i;
    const float s = eg[pe] * rsqrtf(ev[pe] + BN_EPS);
    sc[i] = s;
    of[i] = fmaf(eb[pe] - em[pe], s, ebb[pe]);
  }

  floatx16 acc[MT][NT];
#pragma unroll
  for (int a = 0; a < MT; ++a)
#pragma unroll
    for (int b = 0; b < NT; ++b)
#pragma unroll
      for (int r = 0; r < 16; ++r) acc[a][b][r] = 0.f;

  const _Float16* xb = xin + (size_t)p * LIN * CI;
  // B staging with rotate swizzle: logical octet q of row r -> (q+r)&3.
  auto stage_B = [&](int cic, int buf) {
    for (int c = t; c < XWR * 4; c += 256) {
      const int row = c >> 2, qq = c & 3;
      const int gx = x0 - PAD + row;
      uint4 v = {0u, 0u, 0u, 0u};
      if (gx >= 0 && gx < LIN)
        v = *(const uint4*)(xb + (size_t)gx * CI + cic * 32 + qq * 8);
      *(uint4*)(&Bsh[buf][row * 32 + (((qq + row) & 3) << 3)]) = v;
    }
  };

  const _Float16* Abase = wrp +
      (((size_t)e * NPH) * CO + cob + wm * (MT * 32) + l31) * 32 + lhi * 8;
  half8 Ar[RING][MT][2];
  half8 bf[2][NT][2];

#define LOAD_A(PH, SLOT)                                                     \
  do {                                                                       \
    const int _ph = (PH);                                                    \
    if (_ph < NPH) {                                                         \
      const _Float16* _src = Abase + (size_t)_ph * (CO * 32);                \
      _Pragma("unroll") for (int _mt = 0; _mt < MT; ++_mt)                   \
          _Pragma("unroll") for (int _ks = 0; _ks < 2; ++_ks)                \
              Ar[SLOT][_mt][_ks] =                                           \
          *(const half8*)(_src + _mt * (32 * 32) + _ks * 16);                \
    }                                                                        \
  } while (0)

#define LOAD_BF(BI, BB, DK)                                                  \
  do {                                                                       \
    const _Float16* _bb = (BB);                                              \
    const int _dk = (DK);                                                    \
    _Pragma("unroll") for (int _nt = 0; _nt < NT; ++_nt)                     \
        _Pragma("unroll") for (int _ks = 0; _ks < 2; ++_ks) {                \
      const int _row = wn * (NT * 32) + _nt * 32 + l31 + _dk;                \
      bf[BI][_nt][_ks] = *(const half8*)(                                    \
          _bb + _row * 32 + ((((_ks << 1) + lhi + _row) & 3) << 3));         \
    }                                                                        \
  } while (0)

  stage_B(0, 0);
#pragma unroll
  for (int d = 0; d < RING; ++d) LOAD_A(d, d);
  __syncthreads();
  if (NC > 1) stage_B(1, 1);
  LOAD_BF(0, &Bsh[0][0], 0);

  for (int cic = 0; cic < NC; ++cic) {
    const _Float16* Bb = &Bsh[cic & 1][0];
    const int phb = cic * KP;
#pragma unroll
    for (int d = 0; d < KP; ++d) {
      if (d + 1 < KP) LOAD_BF((d + 1) & 1, Bb, d + 1);
#pragma unroll
      for (int mt = 0; mt < MT; ++mt)
#pragma unroll
        for (int nt = 0; nt < NT; ++nt)
#pragma unroll
          for (int ks = 0; ks < 2; ++ks)
            acc[mt][nt] = __builtin_amdgcn_mfma_f32_32x32x16_f16(
                Ar[d % RING][mt][ks], bf[d & 1][nt][ks], acc[mt][nt], 0, 0, 0);
      LOAD_A(phb + d + RING, d % RING);
    }
    __syncthreads();
    if (cic + 2 < NC) stage_B(cic + 2, cic & 1);
    if (cic + 1 < NC) LOAD_BF(0, &Bsh[(cic + 1) & 1][0], 0);
  }
#undef LOAD_A
#undef LOAD_BF

  // Epilogue: BN + ReLU + maxpool2 (x pairs = adjacent lanes in C layout).
#pragma unroll
  for (int mt = 0; mt < MT; ++mt) {
#pragma unroll
    for (int nt = 0; nt < NT; ++nt) {
#pragma unroll
      for (int rq = 0; rq < 4; ++rq) {
        union { _Float16 h[4]; uint2 u; } pk;
#pragma unroll
        for (int j = 0; j < 4; ++j) {
          const int co_l = wm * (MT * 32) + mt * 32 + 8 * rq + 4 * lhi + j;
          float y = fmaxf(fmaf(acc[mt][nt][rq * 4 + j], sc[co_l], of[co_l]),
                          0.f);
          const float yp = __shfl_xor(y, 1, 64);
          pk.h[j] = (_Float16)fmaxf(y, yp);
        }
        if ((lane & 1) == 0) {
          const int xp = (x0 + wn * (NT * 32) + nt * 32 + l31) >> 1;
          const int co = cob + wm * (MT * 32) + mt * 32 + 8 * rq + 4 * lhi;
          *(uint2*)(out + ((size_t)p * (LIN / 2) + xp) * CO + co) = pk.u;
        }
      }
    }
  }
}

// ---------------------------------------------------------------------------
// Combine: mean over 32 positions of o4 [p][xp][512] fp16, gated sum.
// ---------------------------------------------------------------------------
__global__ __launch_bounds__(256) void combine_kernel(
    const _Float16* __restrict__ out4, const float* __restrict__ pair_g,
    float* __restrict__ g) {
  const int b = blockIdx.x, t = threadIdx.x;
  const float g0 = pair_g[2 * b], g1 = pair_g[2 * b + 1];
  const _Float16* a0 = out4 + (size_t)(2 * b) * 32 * 512;
  const _Float16* a1 = out4 + (size_t)(2 * b + 1) * 32 * 512;
  for (int c = t; c < 512; c += 256) {
    float s0 = 0.f, s1 = 0.f;
    for (int jj = 0; jj < 32; ++jj) {
      s0 += (float)a0[jj * 512 + c];
      s1 += (float)a1[jj * 512 + c];
    }
    g[b * 512 + c] = (g0 * s0 + g1 * s1) * (1.f / 32.f);
  }
}

// ---------------------------------------------------------------------------
// FC head (512->256 relu ->64 relu ->5). One block per sample.
// ---------------------------------------------------------------------------
__global__ __launch_bounds__(256) void head_kernel(
    const float* __restrict__ g, const float* __restrict__ w1,
    const float* __restrict__ b1, const float* __restrict__ w2,
    const float* __restrict__ b2, const float* __restrict__ w3,
    const float* __restrict__ b3, float* __restrict__ out) {
  __shared__ float gl[512];
  __shared__ float h1[256];
  __shared__ float h2[64];
  const int b = blockIdx.x, t = threadIdx.x;
  for (int i = t; i < 512; i += 256) gl[i] = g[b * 512 + i];
  __syncthreads();
  {
    float a = b1[t];
    const float* wr = w1 + (size_t)t * 512;
    for (int k = 0; k < 512; ++k) a = fmaf(gl[k], wr[k], a);
    h1[t] = fmaxf(a, 0.f);
  }
  __syncthreads();
  if (t < 64) {
    float a = b2[t];
    const float* wr = w2 + (size_t)t * 256;
    for (int k = 0; k < 256; ++k) a = fmaf(h1[k], wr[k], a);
    h2[t] = fmaxf(a, 0.f);
  }
  __syncthreads();
  if (t < 5) {
    float a = b3[t];
    const float* wr = w3 + (size_t)t * 64;
    for (int k = 0; k < 64; ++k) a = fmaf(h2[k], wr[k], a);
    out[b * 5 + t] = a;
  }
}

// ---------------------------------------------------------------------------
extern "C" void kernel_launch(void* const* d_in, const int* in_sizes, int n_in,
                              void* d_out, int out_size, void* d_ws,
                              size_t ws_size, hipStream_t stream) {
  const float* x   = (const float*)d_in[0];
  const float* c1w = (const float*)d_in[1];
  const float* c1b = (const float*)d_in[2];
  const float* ew1 = (const float*)d_in[3];
  const float* eb1 = (const float*)d_in[4];
  const float* eg1 = (const float*)d_in[5];
  const float* ebb1= (const float*)d_in[6];
  const float* em1 = (const float*)d_in[7];
  const float* ev1 = (const float*)d_in[8];
  const float* ew2 = (const float*)d_in[9];
  const float* eb2 = (const float*)d_in[10];
  const float* eg2 = (const float*)d_in[11];
  const float* ebb2= (const float*)d_in[12];
  const float* em2 = (const float*)d_in[13];
  const float* ev2 = (const float*)d_in[14];
  const float* ew3 = (const float*)d_in[15];
  const float* eb3 = (const float*)d_in[16];
  const float* eg3 = (const float*)d_in[17];
  const float* ebb3= (const float*)d_in[18];
  const float* em3 = (const float*)d_in[19];
  const float* ev3 = (const float*)d_in[20];
  const float* ew4 = (const float*)d_in[21];
  const float* eb4 = (const float*)d_in[22];
  const float* eg4 = (const float*)d_in[23];
  const float* ebb4= (const float*)d_in[24];
  const float* em4 = (const float*)d_in[25];
  const float* ev4 = (const float*)d_in[26];
  const float* rw  = (const float*)d_in[27];
  const float* rb  = (const float*)d_in[28];
  const float* f1w = (const float*)d_in[29];
  const float* f1b = (const float*)d_in[30];
  const float* f2w = (const float*)d_in[31];
  const float* f2b = (const float*)d_in[32];
  const float* f3w = (const float*)d_in[33];
  const float* f3b = (const float*)d_in[34];
  float* out = (float*)d_out;

  // workspace layout
  float* ws      = (float*)d_ws;
  float* h       = ws;                       // 524288 f32
  float* pooled  = h + 524288;               // 1024
  float* pair_g  = pooled + 1024;            // 128
  int*   pair_e  = (int*)(pair_g + 128);     // 128
  _Float16* o1   = (_Float16*)(ws + 525568);   // 128*256*64
  _Float16* o2   = o1 + 2097152;               // 128*128*128
  _Float16* o3   = o2 + 2097152;               // 128*64*256
  _Float16* o4   = o3 + 2097152;               // 128*32*512
  _Float16* w2r  = o4 + 2097152;               // 8*2*9*128*32   = 589,824
  _Float16* w3r  = w2r + 589824;               // 8*4*12*256*32  = 3,145,728
  _Float16* w4r  = w3r + 3145728;              // 8*8*25*512*32  = 26,214,400
  float* g       = (float*)(w4r + 26214400);   // 64*512 f32

  conv1_kernel<<<64, 256, 0, stream>>>(x, c1w, c1b, h, pooled);
  router_kernel<<<1, 64, 0, stream>>>(pooled, rw, rb, pair_g, pair_e, out + 320);

  repack_kernel<64, 9, 9, 128><<<8 * 2 * 128 * 32 / 256, 256, 0, stream>>>(ew2, w2r);
  repack_kernel<128, 11, 12, 256><<<8 * 4 * 256 * 32 / 256, 256, 0, stream>>>(ew3, w3r);
  repack_kernel<256, 25, 25, 512><<<8 * 8 * 512 * 32 / 256, 256, 0, stream>>>(ew4, w4r);

  conv_block1<<<dim3(8, 128), 256, 0, stream>>>(h, ew1, eb1, eg1, ebb1, em1,
                                                ev1, pair_e, o1);
  // block2: 64->128, L256->128. WM2xWN2, MT2,NT2 (BM=128,XN=128), KP=9,RING=3
  mfma_conv<64, 9, 9, 4, 128, 2, 2, 2, 2, 256, 3>
      <<<dim3(2, 128), 256, 0, stream>>>(o1, w2r, eb2, eg2, ebb2, em2, ev2,
                                         pair_e, o2);
  // block3: 128->256, L128->64. WM4xWN1, MT2,NT2 (BM=256,XN=64), KP=12,RING=3
  mfma_conv<128, 11, 12, 5, 256, 4, 1, 2, 2, 128, 3>
      <<<dim3(2, 128), 256, 0, stream>>>(o2, w3r, eb3, eg3, ebb3, em3, ev3,
                                         pair_e, o3);
  // block4: 256->512, L64->32.  WM4xWN1, MT2,NT2 (BM=256,XN=64), KP=25,RING=5
  mfma_conv<256, 25, 25, 12, 512, 4, 1, 2, 2, 64, 5>
      <<<dim3(2, 128), 256, 0, stream>>>(o3, w4r, eb4, eg4, ebb4, em4, ev4,
                                         pair_e, o4);

  combine_kernel<<<64, 256, 0, stream>>>(o4, pair_g, g);
  head_kernel<<<64, 256, 0, stream>>>(g, f1w, f1b, f2w, f2b, f3w, f3b, out);
}